// Round 17
// baseline (510.724 us; speedup 1.0000x reference)
//
#include <hip/hip_runtime.h>
#include <hip/hip_bf16.h>
#include <hip/hip_cooperative_groups.h>
#include <cstdint>
#include <cstddef>

namespace cg = cooperative_groups;

// ---------------------------------------------------------------------------
// KQV2DPixel: 1x1-conv projections + flash attention, B=8, Cin=64, Cm=32,
// N=4096. fp32 in/out. fp16 QK^T/PV, log2-domain online softmax with
// defer-max, cvt_pkrtz+permlane32_swap P-packing, pair-level bookkeeping,
// ones-MFMA row sums (R13/R16 attn loop, best measured 59.4-59.6us total).
// R17: cooperative single-kernel fusion (proj -> grid.sync -> attn ->
// grid.sync -> reduce) to remove the two kernel-boundary gaps. Fences only
// at phase boundaries (no compute in flight -> avoids R15's fence/compute
// race). Falls back to the UNCHANGED R16 3-kernel path if the cooperative
// launch is rejected. Session lessons: R5 (launch_bounds VGPR cap), R14
// (wave-pressure null), R15 (racing fences 4x), R9 (no-max failed).
// ---------------------------------------------------------------------------

typedef _Float16 f16x8 __attribute__((ext_vector_type(8)));
typedef float  f32x16 __attribute__((ext_vector_type(16)));
typedef float  f32x4  __attribute__((ext_vector_type(4)));

struct alignas(16) U4 { uint32_t w[4]; };
struct alignas(8)  U2 { uint32_t w[2]; };

#define MFMA16(A, B, C) __builtin_amdgcn_mfma_f32_32x32x16_f16((A), (B), (C), 0, 0, 0)

__device__ __forceinline__ uint16_t f2h(float f) {       // RNE f32->f16
    _Float16 h = (_Float16)f;
    return __builtin_bit_cast(uint16_t, h);
}
__device__ __forceinline__ uint16_t f2bf(float f) {      // RNE f32->bf16
    uint32_t u = __builtin_bit_cast(uint32_t, f);
    u += 0x7fffu + ((u >> 16) & 1u);
    return (uint16_t)(u >> 16);
}
__device__ __forceinline__ float bf2f(uint32_t h16) {    // low 16 bits = bf16
    uint32_t u = h16 << 16;
    return __builtin_bit_cast(float, u);
}
__device__ __forceinline__ uint32_t cvtpk16(float lo, float hi) {  // RTZ pack
    auto h2 = __builtin_amdgcn_cvt_pkrtz(lo, hi);        // {lo16, hi16}
    return __builtin_bit_cast(uint32_t, h2);
}
__device__ __forceinline__ void swp(uint32_t& a, uint32_t& b) {
    asm("v_permlane32_swap_b32 %0, %1" : "+v"(a), "+v"(b));
}
__device__ __forceinline__ float ex2(float x) {   // 2^x
    float r;
    asm("v_exp_f32 %0, %1" : "=v"(r) : "v"(x));
    return r;
}
__device__ __forceinline__ float max3(float a, float b, float c) {
    return fmaxf(fmaxf(a, b), c);          // clang fuses to v_max3_f32
}
__device__ __forceinline__ f16x8 ld8(const void* p) {
    return __builtin_bit_cast(f16x8, *(const U4*)p);
}
// async global->LDS, 16B per lane. lds base is wave-uniform; HW adds lane*16.
__device__ __forceinline__ void gload16(const void* g, void* l) {
    __builtin_amdgcn_global_load_lds(
        (const __attribute__((address_space(1))) void*)g,
        (__attribute__((address_space(3))) void*)l, 16, 0, 0);
}

// ===========================================================================
// Standalone 3-kernel path (R16, unchanged) — also the fallback.
// ===========================================================================

__global__ __launch_bounds__(256) void proj_kernel(
    const float* __restrict__ x,
    const float* __restrict__ Wk, const float* __restrict__ bk,
    const float* __restrict__ Wq, const float* __restrict__ bq,
    const float* __restrict__ Wv, const float* __restrict__ bv,
    uint16_t* __restrict__ qf, uint16_t* __restrict__ kf,
    uint16_t* __restrict__ vt)
{
    __shared__ __align__(16) char xtile[64 * 256];   // [ch][px] f32, 16 KB

    const int tid = threadIdx.x;
    const int blk = blockIdx.x;
    const int b   = blk >> 6;
    const int n0  = (blk & 63) << 6;
    const int wv  = __builtin_amdgcn_readfirstlane(tid >> 6);
    const int lane = tid & 63;
    const int px  = lane;
    const int n   = n0 + px;
    const int ob  = wv << 3;

    {
        const char* src = (const char*)(x + (size_t)b * 64 * 4096 + n0)
                        + ((size_t)(16 * wv + (lane >> 4))) * 16384
                        + (lane & 15) * 16;
        char* dst = xtile + wv * 4096;
        #pragma unroll
        for (int j = 0; j < 4; ++j)
            gload16(src + (size_t)(4 * j) * 16384, dst + j * 1024);
    }
    __syncthreads();

    float xv[64];
    #pragma unroll
    for (int ci = 0; ci < 64; ++ci)
        xv[ci] = *(const float*)(xtile + ci * 256 + px * 4);

    #pragma unroll
    for (int pass = 0; pass < 3; ++pass) {
        const float* W    = pass == 0 ? Wk : (pass == 1 ? Wq : Wv);
        const float* bias = pass == 0 ? bk : (pass == 1 ? bq : bv);
        float acc[8];
        #pragma unroll
        for (int o = 0; o < 8; ++o) acc[o] = bias[ob + o];
        #pragma unroll
        for (int o = 0; o < 8; ++o) {
            const float* wr = W + (size_t)(ob + o) * 64;
            #pragma unroll
            for (int ci = 0; ci < 64; ++ci)
                acc[o] = fmaf(wr[ci], xv[ci], acc[o]);
        }
        if (pass == 2) {
            #pragma unroll
            for (int o = 0; o < 8; ++o) {
                int c   = ob + o;
                int nsw = (n & ~0x38) | ((((n >> 3) & 7) ^ (c & 7)) << 3);
                vt[((size_t)(b * 32 + c)) * 4096 + nsw] = f2h(acc[o]);
            }
        } else {
            if (pass == 1) {
                #pragma unroll
                for (int o = 0; o < 8; ++o) acc[o] *= 1.44269504f;
            }
            U4 u;
            #pragma unroll
            for (int t = 0; t < 4; ++t)
                u.w[t] = (uint32_t)f2h(acc[2 * t]) | ((uint32_t)f2h(acc[2 * t + 1]) << 16);
            if (pass == 0) {
                char* rowb = (char*)kf + ((size_t)(b * 4096 + n)) * 64;
                *(U4*)(rowb + ((wv ^ (n & 3)) * 16)) = u;
            } else {
                *(U4*)(qf + ((size_t)(b * 4096 + n)) * 32 + ob) = u;
            }
        }
    }
}

__global__ __launch_bounds__(256, 4) void attn_kernel(
    const uint16_t* __restrict__ qf, const uint16_t* __restrict__ kf,
    const uint16_t* __restrict__ vt, float* __restrict__ out,
    uint16_t* __restrict__ opart, float* __restrict__ mpart,
    float* __restrict__ lpart, int ns)
{
    __shared__ __align__(16) char lds_k[2][2][4096];
    __shared__ __align__(16) char lds_v[2][2][4096];

    const int blk    = blockIdx.x;
    const int b      = blk & 7;
    const int rest   = blk >> 3;
    const int qblk   = rest & 31;
    const int ksp    = rest >> 5;
    const int ntiles = 64 / ns;
    const int kb0    = ksp * ntiles;
    const int niter  = ntiles >> 1;

    const int tid  = threadIdx.x;
    const int wv   = __builtin_amdgcn_readfirstlane(tid >> 6);
    const int lane = tid & 63;
    const int l31  = lane & 31;
    const int h32  = lane >> 5;
    const int qrow = qblk * 128 + wv * 32 + l31;

    f16x8 q0, q1;
    {
        const uint16_t* r = qf + ((size_t)(b * 4096 + qrow)) * 32;
        q0 = ld8(r + h32 * 8);
        q1 = ld8(r + 16 + h32 * 8);
    }
    f16x8 onesv;
    #pragma unroll
    for (int j = 0; j < 8; ++j) onesv[j] = (_Float16)1.f;

    f32x16 oacc, lacc, zf;
    #pragma unroll
    for (int i = 0; i < 16; ++i) { oacc[i] = 0.f; lacc[i] = 0.f; zf[i] = 0.f; }
    float m_run = -3.0e38f;

    const char* gk   = (const char*)kf + ((size_t)b * 4096) * 64;
    const char* gv   = (const char*)vt
                     + ((size_t)(b * 32 + wv * 8 + (lane >> 3))) * 8192
                     + (lane & 7) * 16;
    const char* gk_l = gk + wv * 1024 + lane * 16;

    const int ka0 = l31 * 64 + ((h32 ^ (l31 & 3)) * 16);
    const int ka1 = l31 * 64 + (((2 + h32) ^ (l31 & 3)) * 16);
    int vo[4];
    #pragma unroll
    for (int j = 0; j < 4; ++j)
        vo[j] = l31 * 128 + (((h32 + 2 * j) ^ (l31 & 7)) * 16);

    gload16(gk_l + (size_t)kb0 * 4096,       lds_k[0][0] + wv * 1024);
    gload16(gv   + (size_t)kb0 * 128,        lds_v[0][0] + wv * 1024);
    gload16(gk_l + (size_t)(kb0 + 1) * 4096, lds_k[0][1] + wv * 1024);
    gload16(gv   + (size_t)(kb0 + 1) * 128,  lds_v[0][1] + wv * 1024);

    int p = 0;
    #pragma unroll 1
    for (int it = 0; it < niter; ++it) {
        __syncthreads();

        if (it + 1 < niter) {
            const int tn = kb0 + 2 * it + 2;
            gload16(gk_l + (size_t)tn * 4096,       lds_k[p ^ 1][0] + wv * 1024);
            gload16(gv   + (size_t)tn * 128,        lds_v[p ^ 1][0] + wv * 1024);
            gload16(gk_l + (size_t)(tn + 1) * 4096, lds_k[p ^ 1][1] + wv * 1024);
            gload16(gv   + (size_t)(tn + 1) * 128,  lds_v[p ^ 1][1] + wv * 1024);
        }

        f32x16 sA0, sA1, sB0, sB1;
        {
            const char* lkA = lds_k[p][0];
            f16x8 a0 = ld8(lkA + ka0);
            f16x8 a1 = ld8(lkA + ka1);
            f16x8 c0 = ld8(lkA + 2048 + ka0);
            f16x8 c1 = ld8(lkA + 2048 + ka1);
            sA0 = MFMA16(a0, q0, zf);
            sA1 = MFMA16(c0, q0, zf);
            sA0 = MFMA16(a1, q1, sA0);
            sA1 = MFMA16(c1, q1, sA1);
            const char* lkB = lds_k[p][1];
            f16x8 e0 = ld8(lkB + ka0);
            f16x8 e1 = ld8(lkB + ka1);
            f16x8 g0 = ld8(lkB + 2048 + ka0);
            f16x8 g1 = ld8(lkB + 2048 + ka1);
            sB0 = MFMA16(e0, q0, zf);
            sB1 = MFMA16(g0, q0, zf);
            sB0 = MFMA16(e1, q1, sB0);
            sB1 = MFMA16(g1, q1, sB1);
        }

        float mx[4];
        #pragma unroll
        for (int i = 0; i < 4; ++i)
            mx[i] = max3(max3(sA0[i], sA0[i + 4], sA0[i + 8]),
                         max3(sA0[i + 12], sA1[i], sA1[i + 4]),
                         max3(sA1[i + 8], sA1[i + 12],
                              max3(max3(sB0[i], sB0[i + 4], sB0[i + 8]),
                                   max3(sB0[i + 12], sB1[i], sB1[i + 4]),
                                   fmaxf(sB1[i + 8], sB1[i + 12]))));
        float pm = fmaxf(max3(mx[0], mx[1], mx[2]), mx[3]);
        pm = fmaxf(pm, __shfl_xor(pm, 32));

        if (__any(pm > m_run + 6.f)) {
            float mn  = fmaxf(m_run, pm);
            float scl = ex2(m_run - mn);
            lacc[0] *= scl;
            #pragma unroll
            for (int i = 0; i < 16; ++i) oacc[i] *= scl;
            m_run = mn;
        }

        #pragma unroll
        for (int sl = 0; sl < 2; ++sl) {
            f32x16& s0 = sl ? sB0 : sA0;
            f32x16& s1 = sl ? sB1 : sA1;
            const char* lv = lds_v[p][sl];

            #pragma unroll
            for (int i = 0; i < 16; ++i) {
                s0[i] = ex2(s0[i] - m_run);
                s1[i] = ex2(s1[i] - m_run);
            }

            U4 f1, f2, f3, f4;
            {
                uint32_t A = cvtpk16(s0[0], s0[1]),  B = cvtpk16(s0[4], s0[5]);   swp(A, B);
                uint32_t C = cvtpk16(s0[2], s0[3]),  D = cvtpk16(s0[6], s0[7]);   swp(C, D);
                f1.w[0] = A; f1.w[1] = C; f1.w[2] = B; f1.w[3] = D;
                A = cvtpk16(s0[8], s0[9]);   B = cvtpk16(s0[12], s0[13]);  swp(A, B);
                C = cvtpk16(s0[10], s0[11]); D = cvtpk16(s0[14], s0[15]);  swp(C, D);
                f2.w[0] = A; f2.w[1] = C; f2.w[2] = B; f2.w[3] = D;
                A = cvtpk16(s1[0], s1[1]);   B = cvtpk16(s1[4], s1[5]);    swp(A, B);
                C = cvtpk16(s1[2], s1[3]);   D = cvtpk16(s1[6], s1[7]);    swp(C, D);
                f3.w[0] = A; f3.w[1] = C; f3.w[2] = B; f3.w[3] = D;
                A = cvtpk16(s1[8], s1[9]);   B = cvtpk16(s1[12], s1[13]);  swp(A, B);
                C = cvtpk16(s1[10], s1[11]); D = cvtpk16(s1[14], s1[15]);  swp(C, D);
                f4.w[0] = A; f4.w[1] = C; f4.w[2] = B; f4.w[3] = D;
            }

            {
                f16x8 fa = __builtin_bit_cast(f16x8, f1);
                f16x8 fb = __builtin_bit_cast(f16x8, f2);
                f16x8 fc = __builtin_bit_cast(f16x8, f3);
                f16x8 fd = __builtin_bit_cast(f16x8, f4);
                f16x8 fs = (fa + fb) + (fc + fd);
                lacc = MFMA16(onesv, fs, lacc);
            }

            {
                f16x8 v0 = ld8(lv + vo[0]);
                f16x8 v1 = ld8(lv + vo[1]);
                f16x8 v2 = ld8(lv + vo[2]);
                f16x8 v3 = ld8(lv + vo[3]);
                oacc = MFMA16(v0, __builtin_bit_cast(f16x8, f1), oacc);
                oacc = MFMA16(v1, __builtin_bit_cast(f16x8, f2), oacc);
                oacc = MFMA16(v2, __builtin_bit_cast(f16x8, f3), oacc);
                oacc = MFMA16(v3, __builtin_bit_cast(f16x8, f4), oacc);
            }
        }
        p ^= 1;
    }

    if (ns == 1) {
        const float inv = 1.f / lacc[0];
        float* ob = out + ((size_t)b * 32) * 4096 + qrow;
        #pragma unroll
        for (int i = 0; i < 16; ++i) {
            int c = (i & 3) + 8 * (i >> 2) + 4 * h32;
            ob[(size_t)c * 4096] = oacc[i] * inv;
        }
    } else {
        uint16_t* op = opart + ((size_t)((ksp * 8 + b) * 32)) * 4096 + qrow;
        #pragma unroll
        for (int i = 0; i < 16; ++i) {
            int c = (i & 3) + 8 * (i >> 2) + 4 * h32;
            op[(size_t)c * 4096] = f2bf(oacc[i]);
        }
        if (h32 == 0) {
            mpart[((size_t)(ksp * 8 + b)) * 4096 + qrow] = m_run;
            lpart[((size_t)(ksp * 8 + b)) * 4096 + qrow] = lacc[0];
        }
    }
}

__global__ __launch_bounds__(256) void reduce_kernel(
    const uint16_t* __restrict__ opart, const float* __restrict__ mpart,
    const float* __restrict__ lpart, float* __restrict__ out, int ns)
{
    const int idx = blockIdx.x * 256 + threadIdx.x;
    const int nq  = idx & 1023;
    const int c   = (idx >> 10) & 31;
    const int b   = idx >> 15;
    const size_t noff = (size_t)nq * 4;

    f32x4 M;
    #pragma unroll
    for (int e = 0; e < 4; ++e) M[e] = -3.0e38f;
    for (int s = 0; s < ns; ++s) {
        f32x4 mm = *(const f32x4*)(mpart + ((size_t)(s * 8 + b)) * 4096 + noff);
        #pragma unroll
        for (int e = 0; e < 4; ++e) M[e] = fmaxf(M[e], mm[e]);
    }
    f32x4 L, O;
    #pragma unroll
    for (int e = 0; e < 4; ++e) { L[e] = 0.f; O[e] = 0.f; }
    for (int s = 0; s < ns; ++s) {
        f32x4 mm = *(const f32x4*)(mpart + ((size_t)(s * 8 + b)) * 4096 + noff);
        f32x4 ll = *(const f32x4*)(lpart + ((size_t)(s * 8 + b)) * 4096 + noff);
        U2 uu = *(const U2*)(opart + ((size_t)((s * 8 + b) * 32 + c)) * 4096 + noff);
        float ov[4];
        ov[0] = bf2f(uu.w[0] & 0xffffu);
        ov[1] = bf2f(uu.w[0] >> 16);
        ov[2] = bf2f(uu.w[1] & 0xffffu);
        ov[3] = bf2f(uu.w[1] >> 16);
        #pragma unroll
        for (int e = 0; e < 4; ++e) {
            float w = ex2(mm[e] - M[e]);
            L[e] += ll[e] * w;
            O[e] += ov[e] * w;
        }
    }
    f32x4 r;
    #pragma unroll
    for (int e = 0; e < 4; ++e) r[e] = O[e] / L[e];
    *(f32x4*)(out + ((size_t)(b * 32 + c)) * 4096 + noff) = r;
}

// ===========================================================================
// Fused cooperative kernel: proj -> grid.sync -> attn (ns=4) -> grid.sync
// -> reduce. Grid MUST be 1024 x 256. Shared: 32 KB (proj uses first 16 KB).
// ===========================================================================
__global__ __launch_bounds__(256, 4) void fused_kernel(
    const float* __restrict__ x,
    const float* __restrict__ Wk, const float* __restrict__ bk,
    const float* __restrict__ Wq, const float* __restrict__ bq,
    const float* __restrict__ Wv, const float* __restrict__ bv,
    uint16_t* __restrict__ qf, uint16_t* __restrict__ kf,
    uint16_t* __restrict__ vt, float* __restrict__ out,
    uint16_t* __restrict__ opart, float* __restrict__ mpart,
    float* __restrict__ lpart)
{
    __shared__ __align__(16) char smem[32768];

    cg::grid_group grid = cg::this_grid();
    const int blk  = blockIdx.x;
    const int tid  = threadIdx.x;
    const int wv   = __builtin_amdgcn_readfirstlane(tid >> 6);
    const int lane = tid & 63;

    // ---------------- Phase 1: proj (blocks 0..511) ----------------
    if (blk < 512) {
        char* xtile = smem;                       // [64ch][64px] f32, 16 KB
        const int b   = blk >> 6;
        const int n0  = (blk & 63) << 6;
        const int px  = lane;
        const int n   = n0 + px;
        const int ob  = wv << 3;

        {
            const char* src = (const char*)(x + (size_t)b * 64 * 4096 + n0)
                            + ((size_t)(16 * wv + (lane >> 4))) * 16384
                            + (lane & 15) * 16;
            char* dst = xtile + wv * 4096;
            #pragma unroll
            for (int j = 0; j < 4; ++j)
                gload16(src + (size_t)(4 * j) * 16384, dst + j * 1024);
        }
        __syncthreads();

        float xv[64];
        #pragma unroll
        for (int ci = 0; ci < 64; ++ci)
            xv[ci] = *(const float*)(xtile + ci * 256 + px * 4);

        #pragma unroll
        for (int pass = 0; pass < 3; ++pass) {
            const float* W    = pass == 0 ? Wk : (pass == 1 ? Wq : Wv);
            const float* bias = pass == 0 ? bk : (pass == 1 ? bq : bv);
            float acc[8];
            #pragma unroll
            for (int o = 0; o < 8; ++o) acc[o] = bias[ob + o];
            #pragma unroll
            for (int o = 0; o < 8; ++o) {
                const float* wr = W + (size_t)(ob + o) * 64;
                #pragma unroll
                for (int ci = 0; ci < 64; ++ci)
                    acc[o] = fmaf(wr[ci], xv[ci], acc[o]);
            }
            if (pass == 2) {
                #pragma unroll
                for (int o = 0; o < 8; ++o) {
                    int c   = ob + o;
                    int nsw = (n & ~0x38) | ((((n >> 3) & 7) ^ (c & 7)) << 3);
                    vt[((size_t)(b * 32 + c)) * 4096 + nsw] = f2h(acc[o]);
                }
            } else {
                if (pass == 1) {
                    #pragma unroll
                    for (int o = 0; o < 8; ++o) acc[o] *= 1.44269504f;
                }
                U4 u;
                #pragma unroll
                for (int t = 0; t < 4; ++t)
                    u.w[t] = (uint32_t)f2h(acc[2 * t]) | ((uint32_t)f2h(acc[2 * t + 1]) << 16);
                if (pass == 0) {
                    char* rowb = (char*)kf + ((size_t)(b * 4096 + n)) * 64;
                    *(U4*)(rowb + ((wv ^ (n & 3)) * 16)) = u;
                } else {
                    *(U4*)(qf + ((size_t)(b * 4096 + n)) * 32 + ob) = u;
                }
            }
        }
    }

    __threadfence();     // release proj writes (wbl2) — no compute in flight
    grid.sync();

    // ---------------- Phase 2: attn (all 1024 blocks, ns=4) ----------------
    {
        char* lds_k = smem;              // [pair][slot][4096]
        char* lds_v = smem + 16384;      // [pair][slot][4096]
        const int b      = blk & 7;
        const int rest   = blk >> 3;
        const int qblk   = rest & 31;
        const int ksp    = rest >> 5;            // 0..3
        const int kb0    = ksp * 16;
        const int niter  = 8;
        const int l31    = lane & 31;
        const int h32    = lane >> 5;
        const int qrow   = qblk * 128 + wv * 32 + l31;

        f16x8 q0, q1;
        {
            const uint16_t* r = qf + ((size_t)(b * 4096 + qrow)) * 32;
            q0 = ld8(r + h32 * 8);
            q1 = ld8(r + 16 + h32 * 8);
        }
        f16x8 onesv;
        #pragma unroll
        for (int j = 0; j < 8; ++j) onesv[j] = (_Float16)1.f;

        f32x16 oacc, lacc, zf;
        #pragma unroll
        for (int i = 0; i < 16; ++i) { oacc[i] = 0.f; lacc[i] = 0.f; zf[i] = 0.f; }
        float m_run = -3.0e38f;

        const char* gk   = (const char*)kf + ((size_t)b * 4096) * 64;
        const char* gv   = (const char*)vt
                         + ((size_t)(b * 32 + wv * 8 + (lane >> 3))) * 8192
                         + (lane & 7) * 16;
        const char* gk_l = gk + wv * 1024 + lane * 16;

        const int ka0 = l31 * 64 + ((h32 ^ (l31 & 3)) * 16);
        const int ka1 = l31 * 64 + (((2 + h32) ^ (l31 & 3)) * 16);
        int vo[4];
        #pragma unroll
        for (int j = 0; j < 4; ++j)
            vo[j] = l31 * 128 + (((h32 + 2 * j) ^ (l31 & 7)) * 16);

        gload16(gk_l + (size_t)kb0 * 4096,       lds_k + 0 * 4096 + wv * 1024);
        gload16(gv   + (size_t)kb0 * 128,        lds_v + 0 * 4096 + wv * 1024);
        gload16(gk_l + (size_t)(kb0 + 1) * 4096, lds_k + 1 * 4096 + wv * 1024);
        gload16(gv   + (size_t)(kb0 + 1) * 128,  lds_v + 1 * 4096 + wv * 1024);

        int p = 0;
        #pragma unroll 1
        for (int it = 0; it < niter; ++it) {
            __syncthreads();

            if (it + 1 < niter) {
                const int tn  = kb0 + 2 * it + 2;
                const int np_ = (p ^ 1) * 2;
                gload16(gk_l + (size_t)tn * 4096,       lds_k + (np_ + 0) * 4096 + wv * 1024);
                gload16(gv   + (size_t)tn * 128,        lds_v + (np_ + 0) * 4096 + wv * 1024);
                gload16(gk_l + (size_t)(tn + 1) * 4096, lds_k + (np_ + 1) * 4096 + wv * 1024);
                gload16(gv   + (size_t)(tn + 1) * 128,  lds_v + (np_ + 1) * 4096 + wv * 1024);
            }

            f32x16 sA0, sA1, sB0, sB1;
            {
                const char* lkA = lds_k + (p * 2 + 0) * 4096;
                f16x8 a0 = ld8(lkA + ka0);
                f16x8 a1 = ld8(lkA + ka1);
                f16x8 c0 = ld8(lkA + 2048 + ka0);
                f16x8 c1 = ld8(lkA + 2048 + ka1);
                sA0 = MFMA16(a0, q0, zf);
                sA1 = MFMA16(c0, q0, zf);
                sA0 = MFMA16(a1, q1, sA0);
                sA1 = MFMA16(c1, q1, sA1);
                const char* lkB = lds_k + (p * 2 + 1) * 4096;
                f16x8 e0 = ld8(lkB + ka0);
                f16x8 e1 = ld8(lkB + ka1);
                f16x8 g0 = ld8(lkB + 2048 + ka0);
                f16x8 g1 = ld8(lkB + 2048 + ka1);
                sB0 = MFMA16(e0, q0, zf);
                sB1 = MFMA16(g0, q0, zf);
                sB0 = MFMA16(e1, q1, sB0);
                sB1 = MFMA16(g1, q1, sB1);
            }

            float mx[4];
            #pragma unroll
            for (int i = 0; i < 4; ++i)
                mx[i] = max3(max3(sA0[i], sA0[i + 4], sA0[i + 8]),
                             max3(sA0[i + 12], sA1[i], sA1[i + 4]),
                             max3(sA1[i + 8], sA1[i + 12],
                                  max3(max3(sB0[i], sB0[i + 4], sB0[i + 8]),
                                       max3(sB0[i + 12], sB1[i], sB1[i + 4]),
                                       fmaxf(sB1[i + 8], sB1[i + 12]))));
            float pm = fmaxf(max3(mx[0], mx[1], mx[2]), mx[3]);
            pm = fmaxf(pm, __shfl_xor(pm, 32));

            if (__any(pm > m_run + 6.f)) {
                float mn  = fmaxf(m_run, pm);
                float scl = ex2(m_run - mn);
                lacc[0] *= scl;
                #pragma unroll
                for (int i = 0; i < 16; ++i) oacc[i] *= scl;
                m_run = mn;
            }

            #pragma unroll
            for (int sl = 0; sl < 2; ++sl) {
                f32x16& s0 = sl ? sB0 : sA0;
                f32x16& s1 = sl ? sB1 : sA1;
                const char* lv = lds_v + (p * 2 + sl) * 4096;

                #pragma unroll
                for (int i = 0; i < 16; ++i) {
                    s0[i] = ex2(s0[i] - m_run);
                    s1[i] = ex2(s1[i] - m_run);
                }

                U4 f1, f2, f3, f4;
                {
                    uint32_t A = cvtpk16(s0[0], s0[1]),  B = cvtpk16(s0[4], s0[5]);   swp(A, B);
                    uint32_t C = cvtpk16(s0[2], s0[3]),  D = cvtpk16(s0[6], s0[7]);   swp(C, D);
                    f1.w[0] = A; f1.w[1] = C; f1.w[2] = B; f1.w[3] = D;
                    A = cvtpk16(s0[8], s0[9]);   B = cvtpk16(s0[12], s0[13]);  swp(A, B);
                    C = cvtpk16(s0[10], s0[11]); D = cvtpk16(s0[14], s0[15]);  swp(C, D);
                    f2.w[0] = A; f2.w[1] = C; f2.w[2] = B; f2.w[3] = D;
                    A = cvtpk16(s1[0], s1[1]);   B = cvtpk16(s1[4], s1[5]);    swp(A, B);
                    C = cvtpk16(s1[2], s1[3]);   D = cvtpk16(s1[6], s1[7]);    swp(C, D);
                    f3.w[0] = A; f3.w[1] = C; f3.w[2] = B; f3.w[3] = D;
                    A = cvtpk16(s1[8], s1[9]);   B = cvtpk16(s1[12], s1[13]);  swp(A, B);
                    C = cvtpk16(s1[10], s1[11]); D = cvtpk16(s1[14], s1[15]);  swp(C, D);
                    f4.w[0] = A; f4.w[1] = C; f4.w[2] = B; f4.w[3] = D;
                }

                {
                    f16x8 fa = __builtin_bit_cast(f16x8, f1);
                    f16x8 fb = __builtin_bit_cast(f16x8, f2);
                    f16x8 fc = __builtin_bit_cast(f16x8, f3);
                    f16x8 fd = __builtin_bit_cast(f16x8, f4);
                    f16x8 fs = (fa + fb) + (fc + fd);
                    lacc = MFMA16(onesv, fs, lacc);
                }

                {
                    f16x8 v0 = ld8(lv + vo[0]);
                    f16x8 v1 = ld8(lv + vo[1]);
                    f16x8 v2 = ld8(lv + vo[2]);
                    f16x8 v3 = ld8(lv + vo[3]);
                    oacc = MFMA16(v0, __builtin_bit_cast(f16x8, f1), oacc);
                    oacc = MFMA16(v1, __builtin_bit_cast(f16x8, f2), oacc);
                    oacc = MFMA16(v2, __builtin_bit_cast(f16x8, f3), oacc);
                    oacc = MFMA16(v3, __builtin_bit_cast(f16x8, f4), oacc);
                }
            }
            p ^= 1;
        }

        uint16_t* op = opart + ((size_t)((ksp * 8 + b) * 32)) * 4096 + qrow;
        #pragma unroll
        for (int i = 0; i < 16; ++i) {
            int c = (i & 3) + 8 * (i >> 2) + 4 * h32;
            op[(size_t)c * 4096] = f2bf(oacc[i]);
        }
        if (h32 == 0) {
            mpart[((size_t)(ksp * 8 + b)) * 4096 + qrow] = m_run;
            lpart[((size_t)(ksp * 8 + b)) * 4096 + qrow] = lacc[0];
        }
    }

    __threadfence();     // release partials
    grid.sync();

    // ---------------- Phase 3: reduce (all 1024 blocks, ns=4) ----------------
    {
        const int idx = blk * 256 + tid;
        const int nq  = idx & 1023;
        const int c   = (idx >> 10) & 31;
        const int b   = idx >> 15;
        const size_t noff = (size_t)nq * 4;

        f32x4 M;
        #pragma unroll
        for (int e = 0; e < 4; ++e) M[e] = -3.0e38f;
        for (int s = 0; s < 4; ++s) {
            f32x4 mm = *(const f32x4*)(mpart + ((size_t)(s * 8 + b)) * 4096 + noff);
            #pragma unroll
            for (int e = 0; e < 4; ++e) M[e] = fmaxf(M[e], mm[e]);
        }
        f32x4 L, O;
        #pragma unroll
        for (int e = 0; e < 4; ++e) { L[e] = 0.f; O[e] = 0.f; }
        for (int s = 0; s < 4; ++s) {
            f32x4 mm = *(const f32x4*)(mpart + ((size_t)(s * 8 + b)) * 4096 + noff);
            f32x4 ll = *(const f32x4*)(lpart + ((size_t)(s * 8 + b)) * 4096 + noff);
            U2 uu = *(const U2*)(opart + ((size_t)((s * 8 + b) * 32 + c)) * 4096 + noff);
            float ov[4];
            ov[0] = bf2f(uu.w[0] & 0xffffu);
            ov[1] = bf2f(uu.w[0] >> 16);
            ov[2] = bf2f(uu.w[1] & 0xffffu);
            ov[3] = bf2f(uu.w[1] >> 16);
            #pragma unroll
            for (int e = 0; e < 4; ++e) {
                float w = ex2(mm[e] - M[e]);
                L[e] += ll[e] * w;
                O[e] += ov[e] * w;
            }
        }
        f32x4 r;
        #pragma unroll
        for (int e = 0; e < 4; ++e) r[e] = O[e] / L[e];
        *(f32x4*)(out + ((size_t)(b * 32 + c)) * 4096 + noff) = r;
    }
}

// ---------------------------------------------------------------------------
extern "C" void kernel_launch(void* const* d_in, const int* in_sizes, int n_in,
                              void* d_out, int out_size, void* d_ws, size_t ws_size,
                              hipStream_t stream)
{
    (void)in_sizes; (void)n_in; (void)out_size;
    const float* x  = (const float*)d_in[0];
    const float* Wk = (const float*)d_in[1];
    const float* bk = (const float*)d_in[2];
    const float* Wq = (const float*)d_in[3];
    const float* bq = (const float*)d_in[4];
    const float* Wv = (const float*)d_in[5];
    const float* bv = (const float*)d_in[6];
    float* out = (float*)d_out;

    char* ws = (char*)d_ws;
    const size_t SZ = (size_t)8 * 4096 * 32 * 2;   // 2 MB per fp16 buffer
    uint16_t* qf = (uint16_t*)(ws);
    uint16_t* kf = (uint16_t*)(ws + SZ);
    uint16_t* vt = (uint16_t*)(ws + 2 * SZ);
    const size_t base = 3 * SZ;                    // 6 MB

    const size_t OB  = (size_t)8 * 32 * 4096 * 2;  // 2 MB per split (bf16 O^T)
    const size_t MB_ = (size_t)8 * 4096 * 4;       // 128 KB per split (m or l)
    int ns = 1;
    if      (ws_size >= base + 4 * (OB + 2 * MB_)) ns = 4;
    else if (ws_size >= base + 2 * (OB + 2 * MB_)) ns = 2;

    uint16_t* opart = (uint16_t*)(ws + base);
    float*    mpart = (float*)(ws + base + (size_t)ns * OB);
    float*    lpart = (float*)(ws + base + (size_t)ns * OB + (size_t)ns * MB_);

    bool done = false;
    if (ns == 4) {
        void* args[] = { (void*)&x, (void*)&Wk, (void*)&bk, (void*)&Wq,
                         (void*)&bq, (void*)&Wv, (void*)&bv, (void*)&qf,
                         (void*)&kf, (void*)&vt, (void*)&out, (void*)&opart,
                         (void*)&mpart, (void*)&lpart };
        hipError_t err = hipLaunchCooperativeKernel(
            (const void*)fused_kernel, dim3(1024), dim3(256), args, 0, stream);
        done = (err == hipSuccess);
    }
    if (!done) {
        proj_kernel<<<512, 256, 0, stream>>>(x, Wk, bk, Wq, bq, Wv, bv,
                                             qf, kf, vt);
        attn_kernel<<<ns * 256, 256, 0, stream>>>(qf, kf, vt, out,
                                                  opart, mpart, lpart, ns);
        if (ns > 1)
            reduce_kernel<<<1024, 256, 0, stream>>>(opart, mpart, lpart, out, ns);
    }
}

// Round 18
// 59.327 us; speedup vs baseline: 8.6086x; 8.6086x over previous
//
#include <hip/hip_runtime.h>
#include <hip/hip_bf16.h>
#include <cstdint>
#include <cstddef>

// ---------------------------------------------------------------------------
// KQV2DPixel: 1x1-conv projections + flash attention, B=8, Cin=64, Cm=32,
// N=4096. fp32 in/out. fp16 QK^T/PV, log2-domain online softmax with
// defer-max, cvt_pkrtz+permlane32_swap P-packing, pair-level bookkeeping,
// ones-MFMA row sums. R18 = R13/R16 verbatim (best measured: 59.4-59.6us).
// Session lessons (measured, do not retry):
//  - R5:  __launch_bounds__ 2nd arg caps VGPRs -> scratch spills. Keep (256,4).
//  - R14: wave-pressure null (occ 25->34% but attn 39->43).
//  - R15: in-kernel __threadfence during compute -> cross-XCD L2 writeback
//         destroys concurrent blocks' locality -> 4x regression.
//  - R17: cooperative grid.sync() at 1024 blocks costs ~200us/sync -> 8x.
//         Kernel boundaries ARE the cheap global sync on 8-XCD MI355X.
//  - R9:  no-max softmax failed validation; defer-max (thr=6) is verified.
// ---------------------------------------------------------------------------

typedef _Float16 f16x8 __attribute__((ext_vector_type(8)));
typedef float  f32x16 __attribute__((ext_vector_type(16)));
typedef float  f32x4  __attribute__((ext_vector_type(4)));

struct alignas(16) U4 { uint32_t w[4]; };
struct alignas(8)  U2 { uint32_t w[2]; };

#define MFMA16(A, B, C) __builtin_amdgcn_mfma_f32_32x32x16_f16((A), (B), (C), 0, 0, 0)

__device__ __forceinline__ uint16_t f2h(float f) {       // RNE f32->f16
    _Float16 h = (_Float16)f;
    return __builtin_bit_cast(uint16_t, h);
}
__device__ __forceinline__ uint16_t f2bf(float f) {      // RNE f32->bf16
    uint32_t u = __builtin_bit_cast(uint32_t, f);
    u += 0x7fffu + ((u >> 16) & 1u);
    return (uint16_t)(u >> 16);
}
__device__ __forceinline__ float bf2f(uint32_t h16) {    // low 16 bits = bf16
    uint32_t u = h16 << 16;
    return __builtin_bit_cast(float, u);
}
__device__ __forceinline__ uint32_t cvtpk16(float lo, float hi) {  // RTZ pack
    auto h2 = __builtin_amdgcn_cvt_pkrtz(lo, hi);        // {lo16, hi16}
    return __builtin_bit_cast(uint32_t, h2);
}
__device__ __forceinline__ void swp(uint32_t& a, uint32_t& b) {
    asm("v_permlane32_swap_b32 %0, %1" : "+v"(a), "+v"(b));
}
__device__ __forceinline__ float ex2(float x) {   // 2^x
    float r;
    asm("v_exp_f32 %0, %1" : "=v"(r) : "v"(x));
    return r;
}
__device__ __forceinline__ float max3(float a, float b, float c) {
    return fmaxf(fmaxf(a, b), c);          // clang fuses to v_max3_f32
}
__device__ __forceinline__ f16x8 ld8(const void* p) {
    return __builtin_bit_cast(f16x8, *(const U4*)p);
}
// async global->LDS, 16B per lane. lds base is wave-uniform; HW adds lane*16.
__device__ __forceinline__ void gload16(const void* g, void* l) {
    __builtin_amdgcn_global_load_lds(
        (const __attribute__((address_space(1))) void*)g,
        (__attribute__((address_space(3))) void*)l, 16, 0, 0);
}

// ---------------------------------------------------------------------------
// Kernel 1: projections, LDS-staged. grid 512 x 256; block = 64 pixels.
// Stage x[64ch][64px] (16 KB) via gload_lds (x read ONCE), one barrier,
// then thread (px = tid&63, quarter = tid>>6 wave-uniform) computes 8
// outputs via W s_loads. Store layouts (validated):
//   q: fp16 [B][N][32] (pre-scaled by log2(e)), plain.
//   k: fp16 [B][N][32], 16B-chunk swizzle c4^(n&3) within each 64B row.
//   v: fp16 [B][32][N], 16B-chunk swizzle c8^(c&7) within each 128B seg.
// ---------------------------------------------------------------------------
__global__ __launch_bounds__(256) void proj_kernel(
    const float* __restrict__ x,
    const float* __restrict__ Wk, const float* __restrict__ bk,
    const float* __restrict__ Wq, const float* __restrict__ bq,
    const float* __restrict__ Wv, const float* __restrict__ bv,
    uint16_t* __restrict__ qf, uint16_t* __restrict__ kf,
    uint16_t* __restrict__ vt)
{
    __shared__ __align__(16) char xtile[64 * 256];   // [ch][px] f32, 16 KB

    const int tid = threadIdx.x;
    const int blk = blockIdx.x;
    const int b   = blk >> 6;                 // 64 blocks per batch
    const int n0  = (blk & 63) << 6;          // 64-pixel tile
    const int wv  = __builtin_amdgcn_readfirstlane(tid >> 6);   // quarter, uniform
    const int lane = tid & 63;
    const int px  = lane;
    const int n   = n0 + px;
    const int ob  = wv << 3;                  // 8 outputs per thread

    // ---- stage x tile: wave wv stages ch rows [16wv, 16wv+16) ----
    {
        const char* src = (const char*)(x + (size_t)b * 64 * 4096 + n0)
                        + ((size_t)(16 * wv + (lane >> 4))) * 16384
                        + (lane & 15) * 16;
        char* dst = xtile + wv * 4096;
        #pragma unroll
        for (int j = 0; j < 4; ++j)
            gload16(src + (size_t)(4 * j) * 16384, dst + j * 1024);
    }
    __syncthreads();   // drains gload_lds + barrier; xtile read-only after

    // ---- pull this pixel's 64 channels into registers ----
    float xv[64];
    #pragma unroll
    for (int ci = 0; ci < 64; ++ci)
        xv[ci] = *(const float*)(xtile + ci * 256 + px * 4);

    #pragma unroll
    for (int pass = 0; pass < 3; ++pass) {
        const float* W    = pass == 0 ? Wk : (pass == 1 ? Wq : Wv);
        const float* bias = pass == 0 ? bk : (pass == 1 ? bq : bv);
        float acc[8];
        #pragma unroll
        for (int o = 0; o < 8; ++o) acc[o] = bias[ob + o];
        #pragma unroll
        for (int o = 0; o < 8; ++o) {
            const float* wr = W + (size_t)(ob + o) * 64;   // uniform -> s_load
            #pragma unroll
            for (int ci = 0; ci < 64; ++ci)
                acc[o] = fmaf(wr[ci], xv[ci], acc[o]);
        }
        if (pass == 2) {
            #pragma unroll
            for (int o = 0; o < 8; ++o) {
                int c   = ob + o;
                int nsw = (n & ~0x38) | ((((n >> 3) & 7) ^ (c & 7)) << 3);
                vt[((size_t)(b * 32 + c)) * 4096 + nsw] = f2h(acc[o]);
            }
        } else {
            if (pass == 1) {
                #pragma unroll
                for (int o = 0; o < 8; ++o) acc[o] *= 1.44269504f;   // log2(e)
            }
            U4 u;
            #pragma unroll
            for (int t = 0; t < 4; ++t)
                u.w[t] = (uint32_t)f2h(acc[2 * t]) | ((uint32_t)f2h(acc[2 * t + 1]) << 16);
            if (pass == 0) {
                // swizzled K: chunk c4 = wv -> byte offset (wv^(n&3))*16
                char* rowb = (char*)kf + ((size_t)(b * 4096 + n)) * 64;
                *(U4*)(rowb + ((wv ^ (n & 3)) * 16)) = u;
            } else {
                *(U4*)(qf + ((size_t)(b * 4096 + n)) * 32 + ob) = u;
            }
        }
    }
}

// ---------------------------------------------------------------------------
// Kernel 2: flash attention with K-split. grid ns*256, 256 thr = 4 waves.
// b = blockIdx&7 (XCD-aligned). Per block: 128 q rows x (64/ns) 64-key tiles,
// TWO per barrier (pair). Pair-level softmax bookkeeping + ones-MFMA l.
// ---------------------------------------------------------------------------
__global__ __launch_bounds__(256, 4) void attn_kernel(
    const uint16_t* __restrict__ qf, const uint16_t* __restrict__ kf,
    const uint16_t* __restrict__ vt, float* __restrict__ out,
    uint16_t* __restrict__ opart, float* __restrict__ mpart,
    float* __restrict__ lpart, int ns)
{
    __shared__ __align__(16) char lds_k[2][2][4096];   // [pair][slot] K 64x64B
    __shared__ __align__(16) char lds_v[2][2][4096];   // [pair][slot] V^T 32x128B

    const int blk    = blockIdx.x;
    const int b      = blk & 7;                 // XCD-aligned batch
    const int rest   = blk >> 3;
    const int qblk   = rest & 31;
    const int ksp    = rest >> 5;               // 0..ns-1
    const int ntiles = 64 / ns;                 // even for all ns
    const int kb0    = ksp * ntiles;
    const int niter  = ntiles >> 1;

    const int tid  = threadIdx.x;
    const int wv   = __builtin_amdgcn_readfirstlane(tid >> 6);  // wave-uniform
    const int lane = tid & 63;
    const int l31  = lane & 31;
    const int h32  = lane >> 5;
    const int qrow = qblk * 128 + wv * 32 + l31;

    // Q fragments: B-operand, col(lane&31)=q row, channels 8*h32+j (+16)
    f16x8 q0, q1;
    {
        const uint16_t* r = qf + ((size_t)(b * 4096 + qrow)) * 32;
        q0 = ld8(r + h32 * 8);
        q1 = ld8(r + 16 + h32 * 8);
    }
    f16x8 onesv;
    #pragma unroll
    for (int j = 0; j < 8; ++j) onesv[j] = (_Float16)1.f;

    f32x16 oacc, lacc, zf;
    #pragma unroll
    for (int i = 0; i < 16; ++i) { oacc[i] = 0.f; lacc[i] = 0.f; zf[i] = 0.f; }
    float m_run = -3.0e38f;

    // staging source bases (per-lane).
    const char* gk   = (const char*)kf + ((size_t)b * 4096) * 64;
    const char* gv   = (const char*)vt
                     + ((size_t)(b * 32 + wv * 8 + (lane >> 3))) * 8192
                     + (lane & 7) * 16;
    const char* gk_l = gk + wv * 1024 + lane * 16;

    // LDS read offsets (loop-invariant; XOR matches proj's global swizzle)
    const int ka0 = l31 * 64 + ((h32 ^ (l31 & 3)) * 16);            // ch 8h32..
    const int ka1 = l31 * 64 + (((2 + h32) ^ (l31 & 3)) * 16);      // ch 16+8h32..
    int vo[4];
    #pragma unroll
    for (int j = 0; j < 4; ++j)
        vo[j] = l31 * 128 + (((h32 + 2 * j) ^ (l31 & 7)) * 16);     // keys 16j+8h32..

    // ---- prologue: stage tiles kb0, kb0+1 into pair 0 ----
    gload16(gk_l + (size_t)kb0 * 4096,       lds_k[0][0] + wv * 1024);
    gload16(gv   + (size_t)kb0 * 128,        lds_v[0][0] + wv * 1024);
    gload16(gk_l + (size_t)(kb0 + 1) * 4096, lds_k[0][1] + wv * 1024);
    gload16(gv   + (size_t)(kb0 + 1) * 128,  lds_v[0][1] + wv * 1024);

    int p = 0;
    #pragma unroll 1
    for (int it = 0; it < niter; ++it) {
        __syncthreads();   // drains own gload_lds (vmcnt 0) + block barrier

        if (it + 1 < niter) {   // stage next pair (hides under 2-tile compute)
            const int tn = kb0 + 2 * it + 2;
            gload16(gk_l + (size_t)tn * 4096,       lds_k[p ^ 1][0] + wv * 1024);
            gload16(gv   + (size_t)tn * 128,        lds_v[p ^ 1][0] + wv * 1024);
            gload16(gk_l + (size_t)(tn + 1) * 4096, lds_k[p ^ 1][1] + wv * 1024);
            gload16(gv   + (size_t)(tn + 1) * 128,  lds_v[p ^ 1][1] + wv * 1024);
        }

        // ---- QK^T for BOTH slots (8 MFMAs, independent chains) ----
        f32x16 sA0, sA1, sB0, sB1;
        {
            const char* lkA = lds_k[p][0];
            f16x8 a0 = ld8(lkA + ka0);
            f16x8 a1 = ld8(lkA + ka1);
            f16x8 c0 = ld8(lkA + 2048 + ka0);
            f16x8 c1 = ld8(lkA + 2048 + ka1);
            sA0 = MFMA16(a0, q0, zf);
            sA1 = MFMA16(c0, q0, zf);
            sA0 = MFMA16(a1, q1, sA0);
            sA1 = MFMA16(c1, q1, sA1);
            const char* lkB = lds_k[p][1];
            f16x8 e0 = ld8(lkB + ka0);
            f16x8 e1 = ld8(lkB + ka1);
            f16x8 g0 = ld8(lkB + 2048 + ka0);
            f16x8 g1 = ld8(lkB + 2048 + ka1);
            sB0 = MFMA16(e0, q0, zf);
            sB1 = MFMA16(g0, q0, zf);
            sB0 = MFMA16(e1, q1, sB0);
            sB1 = MFMA16(g1, q1, sB1);
        }

        // ---- ONE softmax bookkeeping per 128 keys (pair level) ----
        float mx[4];
        #pragma unroll
        for (int i = 0; i < 4; ++i)
            mx[i] = max3(max3(sA0[i], sA0[i + 4], sA0[i + 8]),
                         max3(sA0[i + 12], sA1[i], sA1[i + 4]),
                         max3(sA1[i + 8], sA1[i + 12],
                              max3(max3(sB0[i], sB0[i + 4], sB0[i + 8]),
                                   max3(sB0[i + 12], sB1[i], sB1[i + 4]),
                                   fmaxf(sB1[i + 8], sB1[i + 12]))));
        float pm = fmaxf(max3(mx[0], mx[1], mx[2]), mx[3]);
        pm = fmaxf(pm, __shfl_xor(pm, 32));

        if (__any(pm > m_run + 6.f)) {   // rescale only on real growth
            float mn  = fmaxf(m_run, pm);
            float scl = ex2(m_run - mn);
            lacc[0] *= scl;              // only element 0 of lacc is read
            #pragma unroll
            for (int i = 0; i < 16; ++i) oacc[i] *= scl;
            m_run = mn;
        }
        // P = exp2(s - m_run) <= 2^6 = 64: safe in fp16 (max 65504)

        #pragma unroll
        for (int sl = 0; sl < 2; ++sl) {
            f32x16& s0 = sl ? sB0 : sA0;
            f32x16& s1 = sl ? sB1 : sA1;
            const char* lv = lds_v[p][sl];

            #pragma unroll
            for (int i = 0; i < 16; ++i) {
                s0[i] = ex2(s0[i] - m_run);
                s1[i] = ex2(s1[i] - m_run);
            }

            // ---- pack P -> 4 f16x8 B-frags (cvt_pkrtz + permlane) ----
            U4 f1, f2, f3, f4;
            {
                uint32_t A = cvtpk16(s0[0], s0[1]),  B = cvtpk16(s0[4], s0[5]);   swp(A, B);
                uint32_t C = cvtpk16(s0[2], s0[3]),  D = cvtpk16(s0[6], s0[7]);   swp(C, D);
                f1.w[0] = A; f1.w[1] = C; f1.w[2] = B; f1.w[3] = D;
                A = cvtpk16(s0[8], s0[9]);   B = cvtpk16(s0[12], s0[13]);  swp(A, B);
                C = cvtpk16(s0[10], s0[11]); D = cvtpk16(s0[14], s0[15]);  swp(C, D);
                f2.w[0] = A; f2.w[1] = C; f2.w[2] = B; f2.w[3] = D;
                A = cvtpk16(s1[0], s1[1]);   B = cvtpk16(s1[4], s1[5]);    swp(A, B);
                C = cvtpk16(s1[2], s1[3]);   D = cvtpk16(s1[6], s1[7]);    swp(C, D);
                f3.w[0] = A; f3.w[1] = C; f3.w[2] = B; f3.w[3] = D;
                A = cvtpk16(s1[8], s1[9]);   B = cvtpk16(s1[12], s1[13]);  swp(A, B);
                C = cvtpk16(s1[10], s1[11]); D = cvtpk16(s1[14], s1[15]);  swp(C, D);
                f4.w[0] = A; f4.w[1] = C; f4.w[2] = B; f4.w[3] = D;
            }

            // ---- l via ones-MFMA: f_sum = f1+f2+f3+f4 (packed fp16) ----
            {
                f16x8 fa = __builtin_bit_cast(f16x8, f1);
                f16x8 fb = __builtin_bit_cast(f16x8, f2);
                f16x8 fc = __builtin_bit_cast(f16x8, f3);
                f16x8 fd = __builtin_bit_cast(f16x8, f4);
                f16x8 fs = (fa + fb) + (fc + fd);    // v_pk_add_f16 x12
                lacc = MFMA16(onesv, fs, lacc);      // row sums -> lacc[*]
            }

            // ---- PV: O^T[c][q] += V^T * P^T  (4 MFMAs over 64 keys) ----
            {
                f16x8 v0 = ld8(lv + vo[0]);
                f16x8 v1 = ld8(lv + vo[1]);
                f16x8 v2 = ld8(lv + vo[2]);
                f16x8 v3 = ld8(lv + vo[3]);
                oacc = MFMA16(v0, __builtin_bit_cast(f16x8, f1), oacc);
                oacc = MFMA16(v1, __builtin_bit_cast(f16x8, f2), oacc);
                oacc = MFMA16(v2, __builtin_bit_cast(f16x8, f3), oacc);
                oacc = MFMA16(v3, __builtin_bit_cast(f16x8, f4), oacc);
            }
        }
        p ^= 1;
    }

    // ---- epilogue (l = lacc[0]; all lacc rows are identical row-sums) ----
    if (ns == 1) {
        const float inv = 1.f / lacc[0];
        float* ob = out + ((size_t)b * 32) * 4096 + qrow;
        #pragma unroll
        for (int i = 0; i < 16; ++i) {
            int c = (i & 3) + 8 * (i >> 2) + 4 * h32;
            ob[(size_t)c * 4096] = oacc[i] * inv;
        }
    } else {
        uint16_t* op = opart + ((size_t)((ksp * 8 + b) * 32)) * 4096 + qrow;
        #pragma unroll
        for (int i = 0; i < 16; ++i) {
            int c = (i & 3) + 8 * (i >> 2) + 4 * h32;
            op[(size_t)c * 4096] = f2bf(oacc[i]);
        }
        if (h32 == 0) {
            mpart[((size_t)(ksp * 8 + b)) * 4096 + qrow] = m_run;
            lpart[((size_t)(ksp * 8 + b)) * 4096 + qrow] = lacc[0];
        }
    }
}

// ---------------------------------------------------------------------------
// Kernel 3: combine K-split partials (bf16 O, fp32 m/l). thread = (b,c,4px).
// ---------------------------------------------------------------------------
__global__ __launch_bounds__(256) void reduce_kernel(
    const uint16_t* __restrict__ opart, const float* __restrict__ mpart,
    const float* __restrict__ lpart, float* __restrict__ out, int ns)
{
    const int idx = blockIdx.x * 256 + threadIdx.x;   // 262144 quads
    const int nq  = idx & 1023;
    const int c   = (idx >> 10) & 31;
    const int b   = idx >> 15;
    const size_t noff = (size_t)nq * 4;

    f32x4 M;
    #pragma unroll
    for (int e = 0; e < 4; ++e) M[e] = -3.0e38f;
    for (int s = 0; s < ns; ++s) {
        f32x4 mm = *(const f32x4*)(mpart + ((size_t)(s * 8 + b)) * 4096 + noff);
        #pragma unroll
        for (int e = 0; e < 4; ++e) M[e] = fmaxf(M[e], mm[e]);
    }
    f32x4 L, O;
    #pragma unroll
    for (int e = 0; e < 4; ++e) { L[e] = 0.f; O[e] = 0.f; }
    for (int s = 0; s < ns; ++s) {
        f32x4 mm = *(const f32x4*)(mpart + ((size_t)(s * 8 + b)) * 4096 + noff);
        f32x4 ll = *(const f32x4*)(lpart + ((size_t)(s * 8 + b)) * 4096 + noff);
        U2 uu = *(const U2*)(opart + ((size_t)((s * 8 + b) * 32 + c)) * 4096 + noff);
        float ov[4];
        ov[0] = bf2f(uu.w[0] & 0xffffu);
        ov[1] = bf2f(uu.w[0] >> 16);
        ov[2] = bf2f(uu.w[1] & 0xffffu);
        ov[3] = bf2f(uu.w[1] >> 16);
        #pragma unroll
        for (int e = 0; e < 4; ++e) {
            float w = ex2(mm[e] - M[e]);
            L[e] += ll[e] * w;
            O[e] += ov[e] * w;
        }
    }
    f32x4 r;
    #pragma unroll
    for (int e = 0; e < 4; ++e) r[e] = O[e] / L[e];
    *(f32x4*)(out + ((size_t)(b * 32 + c)) * 4096 + noff) = r;
}

// ---------------------------------------------------------------------------
extern "C" void kernel_launch(void* const* d_in, const int* in_sizes, int n_in,
                              void* d_out, int out_size, void* d_ws, size_t ws_size,
                              hipStream_t stream)
{
    (void)in_sizes; (void)n_in; (void)out_size;
    const float* x  = (const float*)d_in[0];
    const float* Wk = (const float*)d_in[1];
    const float* bk = (const float*)d_in[2];
    const float* Wq = (const float*)d_in[3];
    const float* bq = (const float*)d_in[4];
    const float* Wv = (const float*)d_in[5];
    const float* bv = (const float*)d_in[6];
    float* out = (float*)d_out;

    char* ws = (char*)d_ws;
    const size_t SZ = (size_t)8 * 4096 * 32 * 2;   // 2 MB per fp16 buffer
    uint16_t* qf = (uint16_t*)(ws);
    uint16_t* kf = (uint16_t*)(ws + SZ);
    uint16_t* vt = (uint16_t*)(ws + 2 * SZ);
    const size_t base = 3 * SZ;                    // 6 MB

    const size_t OB  = (size_t)8 * 32 * 4096 * 2;  // 2 MB per split (bf16 O^T)
    const size_t MB_ = (size_t)8 * 4096 * 4;       // 128 KB per split (m or l)
    int ns = 1;
    if      (ws_size >= base + 4 * (OB + 2 * MB_)) ns = 4;
    else if (ws_size >= base + 2 * (OB + 2 * MB_)) ns = 2;

    uint16_t* opart = (uint16_t*)(ws + base);
    float*    mpart = (float*)(ws + base + (size_t)ns * OB);
    float*    lpart = (float*)(ws + base + (size_t)ns * OB + (size_t)ns * MB_);

    proj_kernel<<<512, 256, 0, stream>>>(x, Wk, bk, Wq, bq, Wv, bv,
                                         qf, kf, vt);
    attn_kernel<<<ns * 256, 256, 0, stream>>>(qf, kf, vt, out,
                                              opart, mpart, lpart, ns);
    if (ns > 1)
        reduce_kernel<<<1024, 256, 0, stream>>>(opart, mpart, lpart, out, ns);
}